// Round 1
// baseline (1152.915 us; speedup 1.0000x reference)
//
#include <hip/hip_runtime.h>

#define EMB   1024
#define NHEAD 16
#define HS    64
#define BATCH 4
#define SEQ   2048
#define MTOK  (BATCH*SEQ)   // 8192 tokens

typedef __bf16 bf16;
typedef __bf16 bf16x8 __attribute__((ext_vector_type(8)));
typedef __bf16 bf16x4 __attribute__((ext_vector_type(4)));
typedef float  f32x4  __attribute__((ext_vector_type(4)));

#define MFMA16(a,b,c) __builtin_amdgcn_mfma_f32_16x16x32_bf16(a,b,c,0,0,0)

// ---------------- Stage 0a: x fp32 -> bf16 ----------------
__global__ __launch_bounds__(256) void k_convert_x(const float* __restrict__ x,
                                                   bf16* __restrict__ xb) {
    int i = (blockIdx.x * 256 + threadIdx.x) * 4;
    float4 v = *(const float4*)(x + i);
    bf16x4 o;
    o[0] = (bf16)v.x; o[1] = (bf16)v.y; o[2] = (bf16)v.z; o[3] = (bf16)v.w;
    *(bf16x4*)(xb + i) = o;
}

// ---------------- Stage 0b: W fp32 [K][N] -> W^T bf16 [N][K] ----------------
__global__ __launch_bounds__(256) void k_transpose_w(const float* __restrict__ W,
                                                     bf16* __restrict__ Wt) {
    __shared__ float tile[64][65];
    int c0 = blockIdx.x * 64, r0 = blockIdx.y * 64;
    int tx = threadIdx.x & 63, ty = threadIdx.x >> 6;
    #pragma unroll
    for (int r = ty; r < 64; r += 4)
        tile[r][tx] = W[(r0 + r) * EMB + c0 + tx];
    __syncthreads();
    #pragma unroll
    for (int cc = ty; cc < 64; cc += 4)
        Wt[(c0 + cc) * EMB + r0 + tx] = (bf16)tile[tx][cc];
}

// ---------------- Stage 1: fused QKV GEMM ----------------
// A = xb [8192][1024] bf16, B^T = Wt [1024][1024] bf16, computes x@W + bias.
// Q scattered to [B,H,T,HS] (scaled by 1/8), K to [B,H,T,HS], V to [B,H,HS,T].
__global__ __launch_bounds__(256) void k_qkv_gemm(
        const bf16* __restrict__ xb,
        const bf16* __restrict__ Wqt, const bf16* __restrict__ Wkt, const bf16* __restrict__ Wvt,
        const float* __restrict__ bq, const float* __restrict__ bk, const float* __restrict__ bv,
        bf16* __restrict__ Q, bf16* __restrict__ K, bf16* __restrict__ Vt) {
    const int wave = threadIdx.x >> 6;
    const int lane = threadIdx.x & 63;
    const int l15 = lane & 15, quad = lane >> 4;
    const int m0 = blockIdx.x * 64 + wave * 16;
    const int gy = blockIdx.y;           // 0..47
    const int which = gy >> 4;           // 0=q 1=k 2=v
    const int n0 = (gy & 15) * 64;
    const bf16* Wt  = (which == 0) ? Wqt : (which == 1) ? Wkt : Wvt;
    const float* bias = (which == 0) ? bq : (which == 1) ? bk : bv;

    f32x4 acc[4];
    #pragma unroll
    for (int nc = 0; nc < 4; nc++) acc[nc] = (f32x4){0.f, 0.f, 0.f, 0.f};

    const bf16* arow = xb + (m0 + l15) * EMB + quad * 8;
    const bf16* brow = Wt + (n0 + l15) * EMB + quad * 8;
    #pragma unroll 4
    for (int k0 = 0; k0 < EMB; k0 += 32) {
        bf16x8 a = *(const bf16x8*)(arow + k0);
        #pragma unroll
        for (int nc = 0; nc < 4; nc++) {
            bf16x8 b = *(const bf16x8*)(brow + nc * 16 * EMB + k0);
            acc[nc] = MFMA16(a, b, acc[nc]);
        }
    }

    const int row_base = m0 + quad * 4;
    #pragma unroll
    for (int nc = 0; nc < 4; nc++) {
        int col = n0 + nc * 16 + l15;
        float bv_ = bias[col];
        int h = col >> 6, d = col & 63;
        #pragma unroll
        for (int r = 0; r < 4; r++) {
            int row = row_base + r;
            int b_ = row >> 11, t = row & (SEQ - 1);
            float val = acc[nc][r] + bv_;
            if (which == 0) {
                Q[((size_t)(b_ * NHEAD + h) * SEQ + t) * HS + d] = (bf16)(val * 0.125f);
            } else if (which == 1) {
                K[((size_t)(b_ * NHEAD + h) * SEQ + t) * HS + d] = (bf16)val;
            } else {
                Vt[((size_t)(b_ * NHEAD + h) * HS + d) * SEQ + t] = (bf16)val;
            }
        }
    }
}

// ---------------- Stage 2: causal flash attention ----------------
// Q,K: [B*NH, SEQ, 64] bf16 (Q pre-scaled). Vt: [B*NH, 64, SEQ] bf16.
// y out: [B, SEQ, EMB] bf16.
__global__ __launch_bounds__(256) void k_attn(
        const bf16* __restrict__ Q, const bf16* __restrict__ K,
        const bf16* __restrict__ Vt, bf16* __restrict__ y) {
    __shared__ __align__(16) bf16 pbuf[4][16][32];
    const int wave = threadIdx.x >> 6, lane = threadIdx.x & 63;
    const int l15 = lane & 15, quad = lane >> 4;
    const int qt = blockIdx.x;       // 0..31 (q tile of 64)
    const int bh = blockIdx.y;       // 0..63 = b*NH + h
    const int qrow0 = qt * 64 + wave * 16;

    const bf16* Qb = Q + (size_t)bh * SEQ * HS;
    const bf16* Kb = K + (size_t)bh * SEQ * HS;
    const bf16* Vb = Vt + (size_t)bh * HS * SEQ;

    bf16x8 qa0 = *(const bf16x8*)(Qb + (qrow0 + l15) * HS + quad * 8);
    bf16x8 qa1 = *(const bf16x8*)(Qb + (qrow0 + l15) * HS + 32 + quad * 8);

    float m_i[4], l_i[4];
    f32x4 o[4];
    #pragma unroll
    for (int r = 0; r < 4; r++) { m_i[r] = -__builtin_inff(); l_i[r] = 0.f; }
    #pragma unroll
    for (int dc = 0; dc < 4; dc++) o[dc] = (f32x4){0.f, 0.f, 0.f, 0.f};

    const int kv_end = qt * 64 + 63;    // uniform across waves -> barrier-safe
    for (int kv0 = 0; kv0 <= kv_end; kv0 += 32) {
        const bf16* kp = Kb + (kv0 + l15) * HS + quad * 8;
        bf16x8 kb00 = *(const bf16x8*)(kp);
        bf16x8 kb01 = *(const bf16x8*)(kp + 32);
        bf16x8 kb10 = *(const bf16x8*)(kp + 16 * HS);
        bf16x8 kb11 = *(const bf16x8*)(kp + 16 * HS + 32);
        f32x4 s0 = (f32x4){0.f, 0.f, 0.f, 0.f};
        f32x4 s1 = (f32x4){0.f, 0.f, 0.f, 0.f};
        s0 = MFMA16(qa0, kb00, s0); s0 = MFMA16(qa1, kb01, s0);
        s1 = MFMA16(qa0, kb10, s1); s1 = MFMA16(qa1, kb11, s1);

        const int col0 = kv0 + l15, col1 = col0 + 16;
        float p0[4], p1[4];
        #pragma unroll
        for (int r = 0; r < 4; r++) {
            int row = qrow0 + quad * 4 + r;
            float v0 = (col0 <= row) ? s0[r] : -__builtin_inff();
            float v1 = (col1 <= row) ? s1[r] : -__builtin_inff();
            float mr = fmaxf(v0, v1);
            mr = fmaxf(mr, __shfl_xor(mr, 1));
            mr = fmaxf(mr, __shfl_xor(mr, 2));
            mr = fmaxf(mr, __shfl_xor(mr, 4));
            mr = fmaxf(mr, __shfl_xor(mr, 8));
            float mn = fmaxf(m_i[r], mr);
            float alpha = __expf(m_i[r] - mn);
            float e0 = __expf(v0 - mn), e1 = __expf(v1 - mn);
            float rs = e0 + e1;
            rs += __shfl_xor(rs, 1);
            rs += __shfl_xor(rs, 2);
            rs += __shfl_xor(rs, 4);
            rs += __shfl_xor(rs, 8);
            l_i[r] = l_i[r] * alpha + rs;
            m_i[r] = mn;
            p0[r] = e0; p1[r] = e1;
            #pragma unroll
            for (int dc = 0; dc < 4; dc++) o[dc][r] *= alpha;
        }

        // P (C-layout) -> LDS -> A-layout fragment
        #pragma unroll
        for (int r = 0; r < 4; r++) {
            pbuf[wave][quad * 4 + r][l15]      = (bf16)p0[r];
            pbuf[wave][quad * 4 + r][l15 + 16] = (bf16)p1[r];
        }
        __syncthreads();
        bf16x8 pa = *(const bf16x8*)(&pbuf[wave][l15][quad * 8]);

        const bf16* vp = Vb + l15 * SEQ + kv0 + quad * 8;
        #pragma unroll
        for (int dc = 0; dc < 4; dc++) {
            bf16x8 vb = *(const bf16x8*)(vp + dc * 16 * SEQ);
            o[dc] = MFMA16(pa, vb, o[dc]);
        }
    }

    const int h = bh & (NHEAD - 1), b_ = bh >> 4;
    #pragma unroll
    for (int r = 0; r < 4; r++) {
        float inv = 1.f / l_i[r];
        int t = qrow0 + quad * 4 + r;
        bf16* yp = y + ((size_t)(b_ * SEQ + t)) * EMB + h * HS;
        #pragma unroll
        for (int dc = 0; dc < 4; dc++)
            yp[dc * 16 + l15] = (bf16)(o[dc][r] * inv);
    }
}

// ---------------- Stage 3: out projection (fp32 out) ----------------
__global__ __launch_bounds__(256) void k_out_gemm(
        const bf16* __restrict__ y, const bf16* __restrict__ Wot,
        const float* __restrict__ bo, float* __restrict__ out) {
    const int wave = threadIdx.x >> 6;
    const int lane = threadIdx.x & 63;
    const int l15 = lane & 15, quad = lane >> 4;
    const int m0 = blockIdx.x * 64 + wave * 16;
    const int n0 = blockIdx.y * 64;

    f32x4 acc[4];
    #pragma unroll
    for (int nc = 0; nc < 4; nc++) acc[nc] = (f32x4){0.f, 0.f, 0.f, 0.f};

    const bf16* arow = y + (m0 + l15) * EMB + quad * 8;
    const bf16* brow = Wot + (n0 + l15) * EMB + quad * 8;
    #pragma unroll 4
    for (int k0 = 0; k0 < EMB; k0 += 32) {
        bf16x8 a = *(const bf16x8*)(arow + k0);
        #pragma unroll
        for (int nc = 0; nc < 4; nc++) {
            bf16x8 b = *(const bf16x8*)(brow + nc * 16 * EMB + k0);
            acc[nc] = MFMA16(a, b, acc[nc]);
        }
    }

    const int row_base = m0 + quad * 4;
    #pragma unroll
    for (int nc = 0; nc < 4; nc++) {
        int col = n0 + nc * 16 + l15;
        float bv_ = bo[col];
        #pragma unroll
        for (int r = 0; r < 4; r++)
            out[(size_t)(row_base + r) * EMB + col] = acc[nc][r] + bv_;
    }
}

extern "C" void kernel_launch(void* const* d_in, const int* in_sizes, int n_in,
                              void* d_out, int out_size, void* d_ws, size_t ws_size,
                              hipStream_t stream) {
    const float* x  = (const float*)d_in[0];
    const float* Wq = (const float*)d_in[1];
    const float* bq = (const float*)d_in[2];
    const float* Wk = (const float*)d_in[3];
    const float* bk = (const float*)d_in[4];
    const float* Wv = (const float*)d_in[5];
    const float* bv = (const float*)d_in[6];
    const float* Wo = (const float*)d_in[7];
    const float* bo = (const float*)d_in[8];
    float* out = (float*)d_out;

    char* ws = (char*)d_ws;
    bf16* xb  = (bf16*)(ws);                       // 16 MB
    bf16* Wqt = (bf16*)(ws + (16u << 20));         //  2 MB
    bf16* Wkt = (bf16*)(ws + (18u << 20));         //  2 MB
    bf16* Wvt = (bf16*)(ws + (20u << 20));         //  2 MB
    bf16* Wot = (bf16*)(ws + (22u << 20));         //  2 MB
    bf16* Q   = (bf16*)(ws + (24u << 20));         // 16 MB
    bf16* K   = (bf16*)(ws + (40u << 20));         // 16 MB
    bf16* Vt  = (bf16*)(ws + (56u << 20));         // 16 MB
    bf16* y   = (bf16*)(ws + (72u << 20));         // 16 MB  (total 88 MB)

    k_convert_x<<<(MTOK * EMB) / (256 * 4), 256, 0, stream>>>(x, xb);
    dim3 tg(EMB / 64, EMB / 64);
    k_transpose_w<<<tg, 256, 0, stream>>>(Wq, Wqt);
    k_transpose_w<<<tg, 256, 0, stream>>>(Wk, Wkt);
    k_transpose_w<<<tg, 256, 0, stream>>>(Wv, Wvt);
    k_transpose_w<<<tg, 256, 0, stream>>>(Wo, Wot);

    dim3 g1(MTOK / 64, 48);
    k_qkv_gemm<<<g1, 256, 0, stream>>>(xb, Wqt, Wkt, Wvt, bq, bk, bv, Q, K, Vt);

    dim3 g2(SEQ / 64, BATCH * NHEAD);
    k_attn<<<g2, 256, 0, stream>>>(Q, K, Vt, y);

    dim3 g3(MTOK / 64, EMB / 64);
    k_out_gemm<<<g3, 256, 0, stream>>>(y, Wot, bo, out);
}